// Round 6
// baseline (566.858 us; speedup 1.0000x reference)
//
#include <hip/hip_runtime.h>
#include <hip/hip_bf16.h>

#define V 3
#define N 4096
#define D 512
#define H 128
#define C 5
#define LOG2E 1.4426950408889634f

typedef short short8 __attribute__((ext_vector_type(8)));
typedef float floatx4 __attribute__((ext_vector_type(4)));

__device__ __forceinline__ unsigned short f2bf(float f){
  __hip_bfloat16 h = __float2bfloat16(f);
  return *reinterpret_cast<unsigned short*>(&h);
}
// RNE pack of two non-NaN floats to packed bf16x2
__device__ __forceinline__ unsigned int pk_bf16(float a, float b){
  unsigned int ua = __float_as_uint(a), ub = __float_as_uint(b);
  ua += 0x7FFFu + ((ua >> 16) & 1u);
  ub += 0x7FFFu + ((ub >> 16) & 1u);
  return (ua >> 16) | (ub & 0xFFFF0000u);
}

// ---------------- K1: h = data@gac_w (-> hT bf16 [V][H][N]), mlp = data@mlp_w,
// ----------------     e1/e2 = (h.a1, h.a2) * log2e  (K1b folded in) ----------------
#define TN1 16
__global__ __launch_bounds__(256) void k1_gemm(
    const float* __restrict__ data,
    const float* __restrict__ gac_w,
    const float* __restrict__ mlp_w,
    const float* __restrict__ a1, const float* __restrict__ a2,
    unsigned short* __restrict__ hT, float* __restrict__ mlp_out,
    float* __restrict__ e1, float* __restrict__ e2)
{
  const int v = blockIdx.y;
  const int n0 = blockIdx.x * TN1;
  const int t = threadIdx.x;
  const int half = t >> 7, tt = t & 127;   // half 0: d 0..255, half 1: d 256..511
  __shared__ float ds[D][20];              // transposed data tile; 40 KB
  __shared__ float epart[2][2][TN1];       // e1/e2 wave partials
  float* comb = &ds[0][0];                 // aliased post-compute: [2][TN1][H]
  const float* dp = data + ((size_t)v*N + n0)*D;
  for (int j = t; j < TN1*D; j += 256){
    int r = j >> 9, d = j & (D-1);
    ds[d][r] = dp[(size_t)r*D + d];
  }
  __syncthreads();
  float ag[TN1], am[TN1];
  #pragma unroll
  for (int r=0;r<TN1;r++){ ag[r]=0.f; am[r]=0.f; }
  const int d0 = half*256;
  const float* gw = gac_w + (size_t)v*D*H + tt;
  const float* mw = mlp_w + (size_t)v*D*H + tt;
  for (int d=d0; d<d0+256; d++){
    float wg = gw[(size_t)d*H];
    float wm = mw[(size_t)d*H];
    const float4* p = (const float4*)&ds[d][0];
    float4 x0=p[0], x1=p[1], x2=p[2], x3=p[3];
    float xv[16] = {x0.x,x0.y,x0.z,x0.w, x1.x,x1.y,x1.z,x1.w,
                    x2.x,x2.y,x2.z,x2.w, x3.x,x3.y,x3.z,x3.w};
    #pragma unroll
    for (int r=0;r<TN1;r++){
      ag[r] = fmaf(xv[r], wg, ag[r]);
      am[r] = fmaf(xv[r], wm, am[r]);
    }
  }
  __syncthreads();                         // all ds reads done; safe to alias comb
  if (half == 1){
    #pragma unroll
    for (int r=0;r<TN1;r++){
      comb[r*H + tt]          = ag[r];
      comb[TN1*H + r*H + tt]  = am[r];
    }
  }
  __syncthreads();
  if (half == 0){
    float* mp = mlp_out + ((size_t)v*N + n0)*H + tt;
    unsigned short pk[TN1];
    const float a1v = a1[v*H + tt], a2v = a2[v*H + tt];
    #pragma unroll
    for (int r=0;r<TN1;r++){
      ag[r] += comb[r*H + tt];
      am[r] += comb[TN1*H + r*H + tt];
      mp[(size_t)r*H] = am[r];
      pk[r] = f2bf(ag[r]);
    }
    uint4* hp = (uint4*)(hT + ((size_t)v*H + tt)*N + n0);   // transposed bf16 h
    hp[0] = *(uint4*)&pk[0];
    hp[1] = *(uint4*)&pk[8];
    // e1/e2: reduce ag[r]*a1/a2 across the 128 half-0 threads (waves 0,1)
    #pragma unroll
    for (int r=0;r<TN1;r++){
      float s1 = ag[r]*a1v, s2 = ag[r]*a2v;
      #pragma unroll
      for (int o=32;o>0;o>>=1){ s1 += __shfl_down(s1,o); s2 += __shfl_down(s2,o); }
      if ((tt&63)==0){ epart[0][tt>>6][r]=s1; epart[1][tt>>6][r]=s2; }
    }
  }
  __syncthreads();
  if (t < TN1)        e1[(size_t)v*N + n0 + t]       = LOG2E*(epart[0][0][t]    + epart[0][1][t]);
  else if (t < 2*TN1) e2[(size_t)v*N + n0 + (t-TN1)] = LOG2E*(epart[1][0][t-TN1]+ epart[1][1][t-TN1]);
}

// ---------------- K2: masked graph attention via bf16 MFMA ----------------
// Barrier-free: each lane computes its OWN A-fragment (W^T) in registers.
// A[m=lane&15][k=quad*8+j] = exp2(max(y,0.25y)) * mask, y = e1s[r]+e2s[k] (log2e-scaled).
// Wave w owns cols 32w..32w+31 (2 MFMAs/kstep). 4x exp redundancy, zero LDS/barriers.
__global__ __launch_bounds__(256) void k2_attn(
    const unsigned short* __restrict__ hT, const int* __restrict__ adj,
    const float* __restrict__ e1g, const float* __restrict__ e2g,   // pre-scaled by log2e
    const float* __restrict__ mlp_out,
    const float* __restrict__ gac_b, const float* __restrict__ mlp_b,
    float* __restrict__ feat)
{
  const int v = blockIdx.y;
  const int n0 = blockIdx.x * 16;
  const int w = threadIdx.x >> 6, lane = threadIdx.x & 63;
  const int r = lane & 15, quad = lane >> 4;
  const float e1r = e1g[(size_t)v*N + n0 + r];
  const int* aprow = adj + ((size_t)v*N + n0 + r)*N + quad*8;
  const float* e2p = e2g + (size_t)v*N + quad*8;
  const unsigned short* b0p = hT + ((size_t)v*H + 32*w      + r)*N + quad*8;
  const unsigned short* b1p = hT + ((size_t)v*H + 32*w + 16 + r)*N + quad*8;
  floatx4 acc0 = {0.f,0.f,0.f,0.f}, acc1 = {0.f,0.f,0.f,0.f};
  float psum = 0.f;
  #pragma unroll 4
  for (int k0 = 0; k0 < N; k0 += 32){
    int4 aa0 = *(const int4*)(aprow + k0);
    int4 aa1 = *(const int4*)(aprow + k0 + 4);
    float4 ea = *(const float4*)(e2p + k0);
    float4 eb = *(const float4*)(e2p + k0 + 4);
    short8 b8a = *(const short8*)(b0p + k0);
    short8 b8b = *(const short8*)(b1p + k0);
    int   am[8] = {aa0.x,aa0.y,aa0.z,aa0.w, aa1.x,aa1.y,aa1.z,aa1.w};
    float ev[8] = {ea.x,ea.y,ea.z,ea.w, eb.x,eb.y,eb.z,eb.w};
    float wv[8];
    #pragma unroll
    for (int j=0;j<8;j++){
      float y = e1r + ev[j];
      y = fmaxf(y, 0.25f*y);                 // leaky (scale-invariant) BEFORE mask
      float e = exp2f(y);                    // logits O(+-9) scaled: exp2 safe
      wv[j] = (am[j] > 0) ? e : 0.f;         // masked weight exactly 0 (matches ref)
      psum += wv[j];
    }
    union { short8 s; unsigned int u[4]; } a8;
    #pragma unroll
    for (int j=0;j<4;j++) a8.u[j] = pk_bf16(wv[2*j], wv[2*j+1]);
    acc0 = __builtin_amdgcn_mfma_f32_16x16x32_bf16(a8.s, b8a, acc0, 0, 0, 0);
    acc1 = __builtin_amdgcn_mfma_f32_16x16x32_bf16(a8.s, b8b, acc1, 0, 0, 0);
  }
  // row denominators: lanes {r, r+16, r+32, r+48} hold partials of row r
  psum += __shfl_down(psum, 32);
  psum += __shfl_down(psum, 16);             // lanes 0..15: full row sums
  // epilogue: C[row][col], row=(lane>>4)*4+reg, col0=32w+r, col1=col0+16
  const int col0 = 32*w + r;
  const float gb0 = gac_b[v*H + col0], gb1 = gac_b[v*H + col0 + 16];
  const float mb0 = mlp_b[v*H + col0], mb1 = mlp_b[v*H + col0 + 16];
  #pragma unroll
  for (int reg=0; reg<4; reg++){
    const int row = quad*4 + reg;
    const float den = __shfl(psum, row);
    const size_t base = ((size_t)v*N + n0 + row)*H;
    float x0 = acc0[reg]/den + gb0;
    x0 = (x0 >= 0.f) ? x0 : 0.25f*x0;
    feat[base + col0] = x0 + mlp_out[base + col0] + mb0;
    float x1 = acc1[reg]/den + gb1;
    x1 = (x1 >= 0.f) ? x1 : 0.25f*x1;
    feat[base + col0 + 16] = x1 + mlp_out[base + col0 + 16] + mb1;
  }
}

// ---------------- K3: per-node HxH outer-product attention + fc + conf gate ----------------
#define TN3 8
__global__ __launch_bounds__(128) void k3_sgfe(
    const float* __restrict__ feat,
    const float* __restrict__ qw, const float* __restrict__ qb,
    const float* __restrict__ kw, const float* __restrict__ kb,
    const float* __restrict__ vw, const float* __restrict__ vb,
    const float* __restrict__ fcw, const float* __restrict__ fcb,
    const float* __restrict__ confw, const float* __restrict__ confb,
    float* __restrict__ feat2)
{
  const int v = blockIdx.y;
  const int n0 = blockIdx.x * TN3;
  const int t = threadIdx.x;
  const int W = t >> 6, lane = t & 63;
  __shared__ float fsT[H][12];             // feat tile transposed, padded
  __shared__ float Qs[TN3][H];
  __shared__ float2 KVs[TN3][H];
  __shared__ float As2T[H][12];            // agg, [dim][node], padded
  __shared__ float rbuf2[TN3][2];
  const float* fp = feat + ((size_t)v*N + n0)*H + t;
  #pragma unroll
  for (int r=0;r<TN3;r++) fsT[t][r] = fp[(size_t)r*H];
  __syncthreads();
  const float* qwp = qw + (size_t)v*H*H + t;
  const float* kwp = kw + (size_t)v*H*H + t;
  const float* vwp = vw + (size_t)v*H*H + t;
  float Qr[TN3], Kr[TN3], Vr[TN3];
  {
    const float qbv = qb[v*H+t], kbv = kb[v*H+t], vbv = vb[v*H+t];
    #pragma unroll
    for (int r=0;r<TN3;r++){ Qr[r]=qbv; Kr[r]=kbv; Vr[r]=vbv; }
  }
  for (int i=0;i<H;i++){   // one weight sweep computes Q,K,V for all 8 nodes
    float wq = qwp[(size_t)i*H];
    float wk = kwp[(size_t)i*H];
    float wv = vwp[(size_t)i*H];
    float4 f0 = *(const float4*)&fsT[i][0];
    float4 f1 = *(const float4*)&fsT[i][4];
    float fv[8] = {f0.x,f0.y,f0.z,f0.w, f1.x,f1.y,f1.z,f1.w};
    #pragma unroll
    for (int r=0;r<TN3;r++){
      Qr[r] = fmaf(fv[r], wq, Qr[r]);
      Kr[r] = fmaf(fv[r], wk, Kr[r]);
      Vr[r] = fmaf(fv[r], wv, Vr[r]);
    }
  }
  #pragma unroll
  for (int r=0;r<TN3;r++){
    Qs[r][t] = Qr[r];
    KVs[r][t] = make_float2(Kr[r], Vr[r]);
  }
  __syncthreads();
  // attention: wave W handles nodes r = 2*p + W; each lane covers dims lane, lane+64
  const float invs = 0.08838834764831845f;  // 1/sqrt(128)
  #pragma unroll
  for (int p=0;p<4;p++){
    const int r = 2*p + W;
    const float qa = Qs[r][lane]   * invs;
    const float qb2 = Qs[r][lane+64] * invs;
    float sA=0.f, aA=0.f, sB=0.f, aB=0.f;
    const float4* kvp = (const float4*)&KVs[r][0];
    #pragma unroll 4
    for (int oo=0; oo<H/2; oo++){
      float4 kv2 = kvp[oo];                // two (K,V) pairs per b128
      float eA0 = __expf(qa*kv2.x);  sA += eA0; aA = fmaf(eA0, kv2.y, aA);
      float eA1 = __expf(qa*kv2.z);  sA += eA1; aA = fmaf(eA1, kv2.w, aA);
      float eB0 = __expf(qb2*kv2.x); sB += eB0; aB = fmaf(eB0, kv2.y, aB);
      float eB1 = __expf(qb2*kv2.z); sB += eB1; aB = fmaf(eB1, kv2.w, aB);
    }
    As2T[lane][r]    = aA/sA;
    As2T[lane+64][r] = aB/sB;
  }
  __syncthreads();
  // fc: g[r] = sum_i As2T[i][r] * fcw[i][t]  (fcw read ONCE per block)
  const float* fcwp = fcw + (size_t)v*H*H + t;
  const float fcbv = fcb[v*H+t];
  float g[TN3];
  #pragma unroll
  for (int r=0;r<TN3;r++) g[r] = fcbv;
  for (int i=0;i<H;i++){
    float fw = fcwp[(size_t)i*H];
    float4 a0 = *(const float4*)&As2T[i][0];
    float4 a1v = *(const float4*)&As2T[i][4];
    g[0] = fmaf(a0.x, fw, g[0]);  g[1] = fmaf(a0.y, fw, g[1]);
    g[2] = fmaf(a0.z, fw, g[2]);  g[3] = fmaf(a0.w, fw, g[3]);
    g[4] = fmaf(a1v.x, fw, g[4]); g[5] = fmaf(a1v.y, fw, g[5]);
    g[6] = fmaf(a1v.z, fw, g[6]); g[7] = fmaf(a1v.w, fw, g[7]);
  }
  const float cwv = confw[v*H+t];
  const float cbv = confb[v];
  #pragma unroll
  for (int r=0;r<TN3;r++){
    g[r] = fmaxf(g[r], 0.f);
    float psm = g[r]*cwv;
    #pragma unroll
    for (int o=32;o>0;o>>=1) psm += __shfl_down(psm,o);
    if (lane==0) rbuf2[r][W] = psm;
  }
  __syncthreads();
  #pragma unroll
  for (int r=0;r<TN3;r++){
    const float conf = rbuf2[r][0] + rbuf2[r][1] + cbv;
    feat2[((size_t)v*N + n0 + r)*H + t] = g[r]*conf;
  }
}

// ---------------- K4: final classifier [N, V*H] @ [V*H, C] ----------------
__global__ __launch_bounds__(64) void k4_cls(
    const float* __restrict__ feat2,
    const float* __restrict__ mm_w, const float* __restrict__ mm_b,
    float* __restrict__ out)
{
  const int n = blockIdx.x, t = threadIdx.x;
  float a[C] = {0,0,0,0,0};
  for (int j=t; j<V*H; j+=64){
    int vv = j >> 7, hh = j & (H-1);
    float f = feat2[((size_t)vv*N + n)*H + hh];
    #pragma unroll
    for (int c=0;c<C;c++) a[c] = fmaf(f, mm_w[j*C+c], a[c]);
  }
  #pragma unroll
  for (int c=0;c<C;c++){
    #pragma unroll
    for (int o=32;o>0;o>>=1) a[c] += __shfl_down(a[c],o);
  }
  if (t==0){
    #pragma unroll
    for (int c=0;c<C;c++) out[(size_t)n*C+c] = a[c] + mm_b[c];
  }
}

extern "C" void kernel_launch(void* const* d_in, const int* in_sizes, int n_in,
                              void* d_out, int out_size, void* d_ws, size_t ws_size,
                              hipStream_t stream)
{
  (void)in_sizes; (void)n_in; (void)out_size; (void)ws_size;
  const float* data  = (const float*)d_in[0];
  const int*   adj   = (const int*)d_in[1];
  const float* gac_w = (const float*)d_in[2];
  const float* gac_b = (const float*)d_in[3];
  const float* a1    = (const float*)d_in[4];
  const float* a2    = (const float*)d_in[5];
  const float* mlp_w = (const float*)d_in[6];
  const float* mlp_b = (const float*)d_in[7];
  const float* q_w   = (const float*)d_in[8];
  const float* q_b   = (const float*)d_in[9];
  const float* k_w   = (const float*)d_in[10];
  const float* k_b   = (const float*)d_in[11];
  const float* v_w   = (const float*)d_in[12];
  const float* v_b   = (const float*)d_in[13];
  const float* fc_w  = (const float*)d_in[14];
  const float* fc_b  = (const float*)d_in[15];
  const float* cw    = (const float*)d_in[16];
  const float* cb    = (const float*)d_in[17];
  const float* mm_w  = (const float*)d_in[18];
  const float* mm_b  = (const float*)d_in[19];

  float* ws = (float*)d_ws;
  const size_t VNH = (size_t)V*N*H;
  float* mlp   = ws;
  float* feat  = ws + VNH;
  float* feat2 = ws + 2*VNH;
  float* e1    = ws + 3*VNH;
  float* e2    = e1 + (size_t)V*N;
  unsigned short* hT = (unsigned short*)(e2 + (size_t)V*N);  // [V][H][N] bf16

  k1_gemm<<<dim3(N/TN1, V), 256, 0, stream>>>(data, gac_w, mlp_w, a1, a2,
                                              hT, mlp, e1, e2);
  k2_attn<<<dim3(N/16, V),  256, 0, stream>>>(hT, adj, e1, e2, mlp, gac_b, mlp_b, feat);
  k3_sgfe<<<dim3(N/TN3, V), 128, 0, stream>>>(feat, q_w, q_b, k_w, k_b, v_w, v_b,
                                              fc_w, fc_b, cw, cb, feat2);
  k4_cls<<<dim3(N),          64, 0, stream>>>(feat2, mm_w, mm_b, (float*)d_out);
}

// Round 7
// 541.803 us; speedup vs baseline: 1.0462x; 1.0462x over previous
//
#include <hip/hip_runtime.h>
#include <hip/hip_bf16.h>

#define V 3
#define N 4096
#define D 512
#define H 128
#define C 5
#define LOG2E 1.4426950408889634f

typedef short short8 __attribute__((ext_vector_type(8)));
typedef float floatx4 __attribute__((ext_vector_type(4)));

__device__ __forceinline__ unsigned short f2bf(float f){
  __hip_bfloat16 h = __float2bfloat16(f);
  return *reinterpret_cast<unsigned short*>(&h);
}
// RNE pack of two non-NaN floats to packed bf16x2
__device__ __forceinline__ unsigned int pk_bf16(float a, float b){
  unsigned int ua = __float_as_uint(a), ub = __float_as_uint(b);
  ua += 0x7FFFu + ((ua >> 16) & 1u);
  ub += 0x7FFFu + ((ub >> 16) & 1u);
  return (ua >> 16) | (ub & 0xFFFF0000u);
}

// ---------------- K1: h = data@gac_w (-> hT bf16 [V][H][N]), mlp = data@mlp_w,
// ----------------     e1/e2 = (h.a1, h.a2) * log2e  (K1b folded in) ----------------
#define TN1 16
__global__ __launch_bounds__(256) void k1_gemm(
    const float* __restrict__ data,
    const float* __restrict__ gac_w,
    const float* __restrict__ mlp_w,
    const float* __restrict__ a1, const float* __restrict__ a2,
    unsigned short* __restrict__ hT, float* __restrict__ mlp_out,
    float* __restrict__ e1, float* __restrict__ e2)
{
  const int v = blockIdx.y;
  const int n0 = blockIdx.x * TN1;
  const int t = threadIdx.x;
  const int half = t >> 7, tt = t & 127;   // half 0: d 0..255, half 1: d 256..511
  __shared__ float ds[D][20];              // transposed data tile; 40 KB
  __shared__ float epart[2][2][TN1];       // e1/e2 wave partials
  float* comb = &ds[0][0];                 // aliased post-compute: [2][TN1][H]
  const float* dp = data + ((size_t)v*N + n0)*D;
  for (int j = t; j < TN1*D; j += 256){
    int r = j >> 9, d = j & (D-1);
    ds[d][r] = dp[(size_t)r*D + d];
  }
  __syncthreads();
  float ag[TN1], am[TN1];
  #pragma unroll
  for (int r=0;r<TN1;r++){ ag[r]=0.f; am[r]=0.f; }
  const int d0 = half*256;
  const float* gw = gac_w + (size_t)v*D*H + tt;
  const float* mw = mlp_w + (size_t)v*D*H + tt;
  #pragma unroll 4
  for (int d=d0; d<d0+256; d++){
    float wg = gw[(size_t)d*H];
    float wm = mw[(size_t)d*H];
    const float4* p = (const float4*)&ds[d][0];
    float4 x0=p[0], x1=p[1], x2=p[2], x3=p[3];
    float xv[16] = {x0.x,x0.y,x0.z,x0.w, x1.x,x1.y,x1.z,x1.w,
                    x2.x,x2.y,x2.z,x2.w, x3.x,x3.y,x3.z,x3.w};
    #pragma unroll
    for (int r=0;r<TN1;r++){
      ag[r] = fmaf(xv[r], wg, ag[r]);
      am[r] = fmaf(xv[r], wm, am[r]);
    }
  }
  __syncthreads();                         // all ds reads done; safe to alias comb
  if (half == 1){
    #pragma unroll
    for (int r=0;r<TN1;r++){
      comb[r*H + tt]          = ag[r];
      comb[TN1*H + r*H + tt]  = am[r];
    }
  }
  __syncthreads();
  if (half == 0){
    float* mp = mlp_out + ((size_t)v*N + n0)*H + tt;
    unsigned short pk[TN1];
    const float a1v = a1[v*H + tt], a2v = a2[v*H + tt];
    #pragma unroll
    for (int r=0;r<TN1;r++){
      ag[r] += comb[r*H + tt];
      am[r] += comb[TN1*H + r*H + tt];
      mp[(size_t)r*H] = am[r];
      pk[r] = f2bf(ag[r]);
    }
    uint4* hp = (uint4*)(hT + ((size_t)v*H + tt)*N + n0);   // transposed bf16 h
    hp[0] = *(uint4*)&pk[0];
    hp[1] = *(uint4*)&pk[8];
    // e1/e2: reduce ag[r]*a1/a2 across the 128 half-0 threads (waves 0,1)
    #pragma unroll
    for (int r=0;r<TN1;r++){
      float s1 = ag[r]*a1v, s2 = ag[r]*a2v;
      #pragma unroll
      for (int o=32;o>0;o>>=1){ s1 += __shfl_down(s1,o); s2 += __shfl_down(s2,o); }
      if ((tt&63)==0){ epart[0][tt>>6][r]=s1; epart[1][tt>>6][r]=s2; }
    }
  }
  __syncthreads();
  if (t < TN1)        e1[(size_t)v*N + n0 + t]       = LOG2E*(epart[0][0][t]    + epart[0][1][t]);
  else if (t < 2*TN1) e2[(size_t)v*N + n0 + (t-TN1)] = LOG2E*(epart[1][0][t-TN1]+ epart[1][1][t-TN1]);
}

// ---------------- K2: masked graph attention via bf16 MFMA ----------------
// Round-5 producer/consumer (exp computed ONCE) + ping-pong LDS + register
// prefetch of next chunk's adj/e2 -> one barrier per chunk, adj latency hidden
// behind consume+produce of the previous chunk. No max-subtraction (logits
// O(+-9) log2e-scaled, masked weights exactly 0 -> matches ref exp(NEG-max)==0).
#define KC 128
__global__ __launch_bounds__(512) void k2_attn(
    const unsigned short* __restrict__ hT, const int* __restrict__ adj,
    const float* __restrict__ e1g, const float* __restrict__ e2g,   // pre-scaled by log2e
    const float* __restrict__ mlp_out,
    const float* __restrict__ gac_b, const float* __restrict__ mlp_b,
    float* __restrict__ feat)
{
  const int v = blockIdx.y;
  const int n0 = blockIdx.x * 16;
  const int t = threadIdx.x;
  const int w = t >> 6, lane = t & 63;
  __shared__ unsigned short Afrag[2][4][64][8];   // ping-pong fragment buffers, 8 KB
  __shared__ float pden_l[8][16];                 // per-wave per-row denom partials

  // producer mapping: row pr = t&15, sm = t>>4 (0..31), element m = 4*sm + jj
  const int pr = t & 15, sm = t >> 4;
  const int p_ks   = sm >> 3;
  const int p_lane = pr + 16*((sm>>1)&3);
  const int p_j0   = 4*(sm&1);
  const float e1r = e1g[(size_t)v*N + n0 + pr];
  const int* aprow = adj + ((size_t)v*N + n0 + pr)*N;
  const float* e2row = e2g + (size_t)v*N;
  float psum = 0.f;

  // consumer: wave w owns cols w*16 .. w*16+15
  const int col = w*16 + (lane & 15);
  const unsigned short* bcol = hT + ((size_t)v*H + col)*N + ((lane>>4)*8);
  floatx4 acc = {0.f, 0.f, 0.f, 0.f};

  // ---- prefetch + produce chunk 0 ----
  float4 e2v = *(const float4*)(e2row + 4*sm);
  int4   av  = *(const int4*)(aprow + 4*sm);
  {
    float ev[4] = {e2v.x, e2v.y, e2v.z, e2v.w};
    int   aa[4] = {av.x, av.y, av.z, av.w};
    float wv[4];
    #pragma unroll
    for (int jj=0;jj<4;jj++){
      float y = e1r + ev[jj];
      y = fmaxf(y, 0.25f*y);               // leaky (scale-invariant) BEFORE mask
      float e = exp2f(y);
      wv[jj] = (aa[jj] > 0) ? e : 0.f;     // masked weight exactly 0
      psum += wv[jj];
    }
    *(uint2*)&Afrag[0][p_ks][p_lane][p_j0] =
        make_uint2(pk_bf16(wv[0],wv[1]), pk_bf16(wv[2],wv[3]));
  }
  __syncthreads();

  for (int j = 0; j < N/KC; j++){
    const int cur = j & 1;
    const int m0 = j * KC;
    // ---- prefetch chunk j+1 into registers (issues early, used late) ----
    if (j+1 < N/KC){
      e2v = *(const float4*)(e2row + m0 + KC + 4*sm);
      av  = *(const int4*)(aprow + m0 + KC + 4*sm);
    }
    // ---- consume chunk j ----
    #pragma unroll
    for (int ks=0; ks<4; ks++){
      short8 a8 = *(const short8*)&Afrag[cur][ks][lane][0];
      short8 b8 = *(const short8*)(bcol + m0 + ks*32);
      acc = __builtin_amdgcn_mfma_f32_16x16x32_bf16(a8, b8, acc, 0, 0, 0);
    }
    // ---- produce chunk j+1 into the other buffer ----
    if (j+1 < N/KC){
      float ev[4] = {e2v.x, e2v.y, e2v.z, e2v.w};
      int   aa[4] = {av.x, av.y, av.z, av.w};
      float wv[4];
      #pragma unroll
      for (int jj=0;jj<4;jj++){
        float y = e1r + ev[jj];
        y = fmaxf(y, 0.25f*y);
        float e = exp2f(y);
        wv[jj] = (aa[jj] > 0) ? e : 0.f;
        psum += wv[jj];
      }
      *(uint2*)&Afrag[cur^1][p_ks][p_lane][p_j0] =
          make_uint2(pk_bf16(wv[0],wv[1]), pk_bf16(wv[2],wv[3]));
    }
    __syncthreads();
  }
  // denominators: threads with same pr are lanes {pr, pr+16, pr+32, pr+48}
  psum += __shfl_down(psum, 32);
  psum += __shfl_down(psum, 16);
  if (lane < 16) pden_l[w][lane] = psum;
  __syncthreads();
  // epilogue: C[row][col], row = (lane>>4)*4 + reg
  const float gb = gac_b[v*H + col];
  const float mb = mlp_b[v*H + col];
  #pragma unroll
  for (int reg=0; reg<4; reg++){
    const int row = (lane>>4)*4 + reg;
    float den = 0.f;
    #pragma unroll
    for (int k=0;k<8;k++) den += pden_l[k][row];
    float x = acc[reg]/den + gb;
    x = (x >= 0.f) ? x : 0.25f*x;
    const size_t idx = ((size_t)v*N + n0 + row)*H + col;
    feat[idx] = x + mlp_out[idx] + mb;
  }
}

// ---------------- K3: per-node HxH outer-product attention + fc + conf gate ----------------
#define TN3 8
__global__ __launch_bounds__(128) void k3_sgfe(
    const float* __restrict__ feat,
    const float* __restrict__ qw, const float* __restrict__ qb,
    const float* __restrict__ kw, const float* __restrict__ kb,
    const float* __restrict__ vw, const float* __restrict__ vb,
    const float* __restrict__ fcw, const float* __restrict__ fcb,
    const float* __restrict__ confw, const float* __restrict__ confb,
    float* __restrict__ feat2)
{
  const int v = blockIdx.y;
  const int n0 = blockIdx.x * TN3;
  const int t = threadIdx.x;
  const int W = t >> 6, lane = t & 63;
  __shared__ float fsT[H][12];             // feat tile transposed, padded
  __shared__ float Qs[TN3][H];
  __shared__ float2 KVs[TN3][H];
  __shared__ float As2T[H][12];            // agg, [dim][node], padded
  __shared__ float rbuf2[TN3][2];
  const float* fp = feat + ((size_t)v*N + n0)*H + t;
  #pragma unroll
  for (int r=0;r<TN3;r++) fsT[t][r] = fp[(size_t)r*H];
  __syncthreads();
  const float* qwp = qw + (size_t)v*H*H + t;
  const float* kwp = kw + (size_t)v*H*H + t;
  const float* vwp = vw + (size_t)v*H*H + t;
  float Qr[TN3], Kr[TN3], Vr[TN3];
  {
    const float qbv = qb[v*H+t], kbv = kb[v*H+t], vbv = vb[v*H+t];
    #pragma unroll
    for (int r=0;r<TN3;r++){ Qr[r]=qbv; Kr[r]=kbv; Vr[r]=vbv; }
  }
  #pragma unroll 2
  for (int i=0;i<H;i++){   // one weight sweep computes Q,K,V for all 8 nodes
    float wq = qwp[(size_t)i*H];
    float wk = kwp[(size_t)i*H];
    float wv = vwp[(size_t)i*H];
    float4 f0 = *(const float4*)&fsT[i][0];
    float4 f1 = *(const float4*)&fsT[i][4];
    float fv[8] = {f0.x,f0.y,f0.z,f0.w, f1.x,f1.y,f1.z,f1.w};
    #pragma unroll
    for (int r=0;r<TN3;r++){
      Qr[r] = fmaf(fv[r], wq, Qr[r]);
      Kr[r] = fmaf(fv[r], wk, Kr[r]);
      Vr[r] = fmaf(fv[r], wv, Vr[r]);
    }
  }
  #pragma unroll
  for (int r=0;r<TN3;r++){
    Qs[r][t] = Qr[r];
    KVs[r][t] = make_float2(Kr[r], Vr[r]);
  }
  __syncthreads();
  // attention: wave W handles nodes r = 2*p + W; each lane covers dims lane, lane+64
  const float invs = 0.08838834764831845f;  // 1/sqrt(128)
  #pragma unroll
  for (int p=0;p<4;p++){
    const int r = 2*p + W;
    const float qa = Qs[r][lane]   * invs;
    const float qb2 = Qs[r][lane+64] * invs;
    float sA=0.f, aA=0.f, sB=0.f, aB=0.f;
    const float4* kvp = (const float4*)&KVs[r][0];
    #pragma unroll 4
    for (int oo=0; oo<H/2; oo++){
      float4 kv2 = kvp[oo];                // two (K,V) pairs per b128
      float eA0 = __expf(qa*kv2.x);  sA += eA0; aA = fmaf(eA0, kv2.y, aA);
      float eA1 = __expf(qa*kv2.z);  sA += eA1; aA = fmaf(eA1, kv2.w, aA);
      float eB0 = __expf(qb2*kv2.x); sB += eB0; aB = fmaf(eB0, kv2.y, aB);
      float eB1 = __expf(qb2*kv2.z); sB += eB1; aB = fmaf(eB1, kv2.w, aB);
    }
    As2T[lane][r]    = aA/sA;
    As2T[lane+64][r] = aB/sB;
  }
  __syncthreads();
  // fc: g[r] = sum_i As2T[i][r] * fcw[i][t]  (fcw read ONCE per block)
  const float* fcwp = fcw + (size_t)v*H*H + t;
  const float fcbv = fcb[v*H+t];
  float g[TN3];
  #pragma unroll
  for (int r=0;r<TN3;r++) g[r] = fcbv;
  #pragma unroll 2
  for (int i=0;i<H;i++){
    float fw = fcwp[(size_t)i*H];
    float4 a0 = *(const float4*)&As2T[i][0];
    float4 a1v = *(const float4*)&As2T[i][4];
    g[0] = fmaf(a0.x, fw, g[0]);  g[1] = fmaf(a0.y, fw, g[1]);
    g[2] = fmaf(a0.z, fw, g[2]);  g[3] = fmaf(a0.w, fw, g[3]);
    g[4] = fmaf(a1v.x, fw, g[4]); g[5] = fmaf(a1v.y, fw, g[5]);
    g[6] = fmaf(a1v.z, fw, g[6]); g[7] = fmaf(a1v.w, fw, g[7]);
  }
  const float cwv = confw[v*H+t];
  const float cbv = confb[v];
  #pragma unroll
  for (int r=0;r<TN3;r++){
    g[r] = fmaxf(g[r], 0.f);
    float psm = g[r]*cwv;
    #pragma unroll
    for (int o=32;o>0;o>>=1) psm += __shfl_down(psm,o);
    if (lane==0) rbuf2[r][W] = psm;
  }
  __syncthreads();
  #pragma unroll
  for (int r=0;r<TN3;r++){
    const float conf = rbuf2[r][0] + rbuf2[r][1] + cbv;
    feat2[((size_t)v*N + n0 + r)*H + t] = g[r]*conf;
  }
}

// ---------------- K4: final classifier [N, V*H] @ [V*H, C] ----------------
__global__ __launch_bounds__(64) void k4_cls(
    const float* __restrict__ feat2,
    const float* __restrict__ mm_w, const float* __restrict__ mm_b,
    float* __restrict__ out)
{
  const int n = blockIdx.x, t = threadIdx.x;
  float a[C] = {0,0,0,0,0};
  for (int j=t; j<V*H; j+=64){
    int vv = j >> 7, hh = j & (H-1);
    float f = feat2[((size_t)vv*N + n)*H + hh];
    #pragma unroll
    for (int c=0;c<C;c++) a[c] = fmaf(f, mm_w[j*C+c], a[c]);
  }
  #pragma unroll
  for (int c=0;c<C;c++){
    #pragma unroll
    for (int o=32;o>0;o>>=1) a[c] += __shfl_down(a[c],o);
  }
  if (t==0){
    #pragma unroll
    for (int c=0;c<C;c++) out[(size_t)n*C+c] = a[c] + mm_b[c];
  }
}

extern "C" void kernel_launch(void* const* d_in, const int* in_sizes, int n_in,
                              void* d_out, int out_size, void* d_ws, size_t ws_size,
                              hipStream_t stream)
{
  (void)in_sizes; (void)n_in; (void)out_size; (void)ws_size;
  const float* data  = (const float*)d_in[0];
  const int*   adj   = (const int*)d_in[1];
  const float* gac_w = (const float*)d_in[2];
  const float* gac_b = (const float*)d_in[3];
  const float* a1    = (const float*)d_in[4];
  const float* a2    = (const float*)d_in[5];
  const float* mlp_w = (const float*)d_in[6];
  const float* mlp_b = (const float*)d_in[7];
  const float* q_w   = (const float*)d_in[8];
  const float* q_b   = (const float*)d_in[9];
  const float* k_w   = (const float*)d_in[10];
  const float* k_b   = (const float*)d_in[11];
  const float* v_w   = (const float*)d_in[12];
  const float* v_b   = (const float*)d_in[13];
  const float* fc_w  = (const float*)d_in[14];
  const float* fc_b  = (const float*)d_in[15];
  const float* cw    = (const float*)d_in[16];
  const float* cb    = (const float*)d_in[17];
  const float* mm_w  = (const float*)d_in[18];
  const float* mm_b  = (const float*)d_in[19];

  float* ws = (float*)d_ws;
  const size_t VNH = (size_t)V*N*H;
  float* mlp   = ws;
  float* feat  = ws + VNH;
  float* feat2 = ws + 2*VNH;
  float* e1    = ws + 3*VNH;
  float* e2    = e1 + (size_t)V*N;
  unsigned short* hT = (unsigned short*)(e2 + (size_t)V*N);  // [V][H][N] bf16

  k1_gemm<<<dim3(N/TN1, V), 256, 0, stream>>>(data, gac_w, mlp_w, a1, a2,
                                              hT, mlp, e1, e2);
  k2_attn<<<dim3(N/16, V),  512, 0, stream>>>(hT, adj, e1, e2, mlp, gac_b, mlp_b, feat);
  k3_sgfe<<<dim3(N/TN3, V), 128, 0, stream>>>(feat, q_w, q_b, k_w, k_b, v_w, v_b,
                                              fc_w, fc_b, cw, cb, feat2);
  k4_cls<<<dim3(N),          64, 0, stream>>>(feat2, mm_w, mm_b, (float*)d_out);
}

// Round 8
// 501.195 us; speedup vs baseline: 1.1310x; 1.0810x over previous
//
#include <hip/hip_runtime.h>
#include <hip/hip_bf16.h>

#define V 3
#define N 4096
#define D 512
#define H 128
#define C 5
#define LOG2E 1.4426950408889634f

typedef short short8 __attribute__((ext_vector_type(8)));
typedef float floatx4 __attribute__((ext_vector_type(4)));
typedef int   intx4  __attribute__((ext_vector_type(4)));

__device__ __forceinline__ unsigned short f2bf(float f){
  __hip_bfloat16 h = __float2bfloat16(f);
  return *reinterpret_cast<unsigned short*>(&h);
}
// RNE pack of two non-NaN floats to packed bf16x2
__device__ __forceinline__ unsigned int pk_bf16(float a, float b){
  unsigned int ua = __float_as_uint(a), ub = __float_as_uint(b);
  ua += 0x7FFFu + ((ua >> 16) & 1u);
  ub += 0x7FFFu + ((ub >> 16) & 1u);
  return (ua >> 16) | (ub & 0xFFFF0000u);
}

// ---------------- K1: h = data@gac_w (-> hT bf16 [V][H][N]), mlp = data@mlp_w,
// ----------------     e1/e2 = (h.a1, h.a2) * log2e  (K1b folded in) ----------------
#define TN1 16
__global__ __launch_bounds__(256) void k1_gemm(
    const float* __restrict__ data,
    const float* __restrict__ gac_w,
    const float* __restrict__ mlp_w,
    const float* __restrict__ a1, const float* __restrict__ a2,
    unsigned short* __restrict__ hT, float* __restrict__ mlp_out,
    float* __restrict__ e1, float* __restrict__ e2)
{
  const int v = blockIdx.y;
  const int n0 = blockIdx.x * TN1;
  const int t = threadIdx.x;
  const int half = t >> 7, tt = t & 127;   // half 0: d 0..255, half 1: d 256..511
  __shared__ float ds[D][20];              // transposed data tile; 40 KB
  __shared__ float epart[2][2][TN1];       // e1/e2 wave partials
  float* comb = &ds[0][0];                 // aliased post-compute: [2][TN1][H]
  const float* dp = data + ((size_t)v*N + n0)*D;
  for (int j = t; j < TN1*D; j += 256){
    int r = j >> 9, d = j & (D-1);
    ds[d][r] = dp[(size_t)r*D + d];
  }
  __syncthreads();
  float ag[TN1], am[TN1];
  #pragma unroll
  for (int r=0;r<TN1;r++){ ag[r]=0.f; am[r]=0.f; }
  const int d0 = half*256;
  const float* gw = gac_w + (size_t)v*D*H + tt;
  const float* mw = mlp_w + (size_t)v*D*H + tt;
  for (int d=d0; d<d0+256; d++){
    float wg = gw[(size_t)d*H];
    float wm = mw[(size_t)d*H];
    const float4* p = (const float4*)&ds[d][0];
    float4 x0=p[0], x1=p[1], x2=p[2], x3=p[3];
    float xv[16] = {x0.x,x0.y,x0.z,x0.w, x1.x,x1.y,x1.z,x1.w,
                    x2.x,x2.y,x2.z,x2.w, x3.x,x3.y,x3.z,x3.w};
    #pragma unroll
    for (int r=0;r<TN1;r++){
      ag[r] = fmaf(xv[r], wg, ag[r]);
      am[r] = fmaf(xv[r], wm, am[r]);
    }
  }
  __syncthreads();                         // all ds reads done; safe to alias comb
  if (half == 1){
    #pragma unroll
    for (int r=0;r<TN1;r++){
      comb[r*H + tt]          = ag[r];
      comb[TN1*H + r*H + tt]  = am[r];
    }
  }
  __syncthreads();
  if (half == 0){
    float* mp = mlp_out + ((size_t)v*N + n0)*H + tt;
    unsigned short pk[TN1];
    const float a1v = a1[v*H + tt], a2v = a2[v*H + tt];
    #pragma unroll
    for (int r=0;r<TN1;r++){
      ag[r] += comb[r*H + tt];
      am[r] += comb[TN1*H + r*H + tt];
      mp[(size_t)r*H] = am[r];
      pk[r] = f2bf(ag[r]);
    }
    uint4* hp = (uint4*)(hT + ((size_t)v*H + tt)*N + n0);   // transposed bf16 h
    hp[0] = *(uint4*)&pk[0];
    hp[1] = *(uint4*)&pk[8];
    // e1/e2: reduce ag[r]*a1/a2 across the 128 half-0 threads (waves 0,1)
    #pragma unroll
    for (int r=0;r<TN1;r++){
      float s1 = ag[r]*a1v, s2 = ag[r]*a2v;
      #pragma unroll
      for (int o=32;o>0;o>>=1){ s1 += __shfl_down(s1,o); s2 += __shfl_down(s2,o); }
      if ((tt&63)==0){ epart[0][tt>>6][r]=s1; epart[1][tt>>6][r]=s2; }
    }
  }
  __syncthreads();
  if (t < TN1)        e1[(size_t)v*N + n0 + t]       = LOG2E*(epart[0][0][t]    + epart[0][1][t]);
  else if (t < 2*TN1) e2[(size_t)v*N + n0 + (t-TN1)] = LOG2E*(epart[1][0][t-TN1]+ epart[1][1][t-TN1]);
}

// ---------------- K2: masked graph attention via bf16 MFMA ----------------
// Producer/consumer + ping-pong LDS + register prefetch. Changes vs r7:
//  * adj loads NON-TEMPORAL (201 MB once-read stream must not evict hT from L2)
//  * producer mapping: each 32-lane half reads one contiguous 512B adj segment
//    (row = t>>5, k-slot = t&31) -> clean HBM streaming
//  * denominators now wave-local per row (row's whole K lives in one wave)
#define KC 128
__global__ __launch_bounds__(512) void k2_attn(
    const unsigned short* __restrict__ hT, const int* __restrict__ adj,
    const float* __restrict__ e1g, const float* __restrict__ e2g,   // pre-scaled by log2e
    const float* __restrict__ mlp_out,
    const float* __restrict__ gac_b, const float* __restrict__ mlp_b,
    float* __restrict__ feat)
{
  const int v = blockIdx.y;
  const int n0 = blockIdx.x * 16;
  const int t = threadIdx.x;
  const int w = t >> 6, lane = t & 63;
  __shared__ unsigned short Afrag[2][4][64][8];   // ping-pong fragment buffers, 8 KB
  __shared__ float pden[16];                      // per-row denominators

  // producer mapping: row pr = t>>5 (0..15), slot s = t&31 -> k = 4s..4s+3
  const int pr = t >> 5, s = t & 31;
  const int p_ks   = s >> 3;                 // kstep 0..3
  const int p_lane = pr + 16*((s&7)>>1);     // fragment lane
  const int p_j0   = 4*(s&1);
  const float e1r = e1g[(size_t)v*N + n0 + pr];
  const intx4* aprow = (const intx4*)(adj + ((size_t)v*N + n0 + pr)*N) + s;
  const float* e2row = e2g + (size_t)v*N + 4*s;
  float psum = 0.f;

  // consumer: wave w owns cols w*16 .. w*16+15
  const int col = w*16 + (lane & 15);
  const unsigned short* bcol = hT + ((size_t)v*H + col)*N + ((lane>>4)*8);
  floatx4 acc = {0.f, 0.f, 0.f, 0.f};

  // ---- prefetch + produce chunk 0 ----
  intx4  av  = __builtin_nontemporal_load(aprow);
  float4 e2v = *(const float4*)e2row;
  {
    float ev[4] = {e2v.x, e2v.y, e2v.z, e2v.w};
    float wv[4];
    #pragma unroll
    for (int jj=0;jj<4;jj++){
      float y = e1r + ev[jj];
      y = fmaxf(y, 0.25f*y);               // leaky (scale-invariant) BEFORE mask
      float e = exp2f(y);
      wv[jj] = (av[jj] > 0) ? e : 0.f;     // masked weight exactly 0
      psum += wv[jj];
    }
    *(uint2*)&Afrag[0][p_ks][p_lane][p_j0] =
        make_uint2(pk_bf16(wv[0],wv[1]), pk_bf16(wv[2],wv[3]));
  }
  __syncthreads();

  for (int j = 0; j < N/KC; j++){
    const int cur = j & 1;
    const int m0 = j * KC;
    // ---- prefetch chunk j+1 into registers (issues early, used late) ----
    if (j+1 < N/KC){
      av  = __builtin_nontemporal_load(aprow + (m0 + KC)/4);
      e2v = *(const float4*)(e2row + m0 + KC);
    }
    // ---- consume chunk j ----
    #pragma unroll
    for (int ks=0; ks<4; ks++){
      short8 a8 = *(const short8*)&Afrag[cur][ks][lane][0];
      short8 b8 = *(const short8*)(bcol + m0 + ks*32);
      acc = __builtin_amdgcn_mfma_f32_16x16x32_bf16(a8, b8, acc, 0, 0, 0);
    }
    // ---- produce chunk j+1 into the other buffer ----
    if (j+1 < N/KC){
      float ev[4] = {e2v.x, e2v.y, e2v.z, e2v.w};
      float wv[4];
      #pragma unroll
      for (int jj=0;jj<4;jj++){
        float y = e1r + ev[jj];
        y = fmaxf(y, 0.25f*y);
        float e = exp2f(y);
        wv[jj] = (av[jj] > 0) ? e : 0.f;
        psum += wv[jj];
      }
      *(uint2*)&Afrag[cur^1][p_ks][p_lane][p_j0] =
          make_uint2(pk_bf16(wv[0],wv[1]), pk_bf16(wv[2],wv[3]));
    }
    __syncthreads();
  }
  // row denominators: row pr's K-range is covered entirely by one 32-lane half
  psum += __shfl_down(psum, 16);
  psum += __shfl_down(psum, 8);
  psum += __shfl_down(psum, 4);
  psum += __shfl_down(psum, 2);
  psum += __shfl_down(psum, 1);
  if ((lane & 31) == 0) pden[2*w + (lane>>5)] = psum;
  __syncthreads();
  // epilogue: C[row][col], row = (lane>>4)*4 + reg
  const float gb = gac_b[v*H + col];
  const float mb = mlp_b[v*H + col];
  #pragma unroll
  for (int reg=0; reg<4; reg++){
    const int row = (lane>>4)*4 + reg;
    const float den = pden[row];
    float x = acc[reg]/den + gb;
    x = (x >= 0.f) ? x : 0.25f*x;
    const size_t idx = ((size_t)v*N + n0 + row)*H + col;
    feat[idx] = x + mlp_out[idx] + mb;
  }
}

// ---------------- K3: per-node HxH outer-product attention + fc + conf gate ----------------
#define TN3 8
__global__ __launch_bounds__(128) void k3_sgfe(
    const float* __restrict__ feat,
    const float* __restrict__ qw, const float* __restrict__ qb,
    const float* __restrict__ kw, const float* __restrict__ kb,
    const float* __restrict__ vw, const float* __restrict__ vb,
    const float* __restrict__ fcw, const float* __restrict__ fcb,
    const float* __restrict__ confw, const float* __restrict__ confb,
    float* __restrict__ feat2)
{
  const int v = blockIdx.y;
  const int n0 = blockIdx.x * TN3;
  const int t = threadIdx.x;
  const int W = t >> 6, lane = t & 63;
  __shared__ float fsT[H][12];             // feat tile transposed, padded
  __shared__ float Qs[TN3][H];
  __shared__ float2 KVs[TN3][H];
  __shared__ float As2T[H][12];            // agg, [dim][node], padded
  __shared__ float rbuf2[TN3][2];
  const float* fp = feat + ((size_t)v*N + n0)*H + t;
  #pragma unroll
  for (int r=0;r<TN3;r++) fsT[t][r] = fp[(size_t)r*H];
  __syncthreads();
  const float* qwp = qw + (size_t)v*H*H + t;
  const float* kwp = kw + (size_t)v*H*H + t;
  const float* vwp = vw + (size_t)v*H*H + t;
  float Qr[TN3], Kr[TN3], Vr[TN3];
  {
    const float qbv = qb[v*H+t], kbv = kb[v*H+t], vbv = vb[v*H+t];
    #pragma unroll
    for (int r=0;r<TN3;r++){ Qr[r]=qbv; Kr[r]=kbv; Vr[r]=vbv; }
  }
  for (int i=0;i<H;i++){   // one weight sweep computes Q,K,V for all 8 nodes
    float wq = qwp[(size_t)i*H];
    float wk = kwp[(size_t)i*H];
    float wv = vwp[(size_t)i*H];
    float4 f0 = *(const float4*)&fsT[i][0];
    float4 f1 = *(const float4*)&fsT[i][4];
    float fv[8] = {f0.x,f0.y,f0.z,f0.w, f1.x,f1.y,f1.z,f1.w};
    #pragma unroll
    for (int r=0;r<TN3;r++){
      Qr[r] = fmaf(fv[r], wq, Qr[r]);
      Kr[r] = fmaf(fv[r], wk, Kr[r]);
      Vr[r] = fmaf(fv[r], wv, Vr[r]);
    }
  }
  #pragma unroll
  for (int r=0;r<TN3;r++){
    Qs[r][t] = Qr[r];
    KVs[r][t] = make_float2(Kr[r], Vr[r]);
  }
  __syncthreads();
  // attention: wave W handles nodes r = 2*p + W; each lane covers dims lane, lane+64
  const float invs = 0.08838834764831845f;  // 1/sqrt(128)
  #pragma unroll
  for (int p=0;p<4;p++){
    const int r = 2*p + W;
    const float qa = Qs[r][lane]   * invs;
    const float qb2 = Qs[r][lane+64] * invs;
    float sA=0.f, aA=0.f, sB=0.f, aB=0.f;
    const float4* kvp = (const float4*)&KVs[r][0];
    #pragma unroll 4
    for (int oo=0; oo<H/2; oo++){
      float4 kv2 = kvp[oo];                // two (K,V) pairs per b128
      float eA0 = __expf(qa*kv2.x);  sA += eA0; aA = fmaf(eA0, kv2.y, aA);
      float eA1 = __expf(qa*kv2.z);  sA += eA1; aA = fmaf(eA1, kv2.w, aA);
      float eB0 = __expf(qb2*kv2.x); sB += eB0; aB = fmaf(eB0, kv2.y, aB);
      float eB1 = __expf(qb2*kv2.z); sB += eB1; aB = fmaf(eB1, kv2.w, aB);
    }
    As2T[lane][r]    = aA/sA;
    As2T[lane+64][r] = aB/sB;
  }
  __syncthreads();
  // fc: g[r] = sum_i As2T[i][r] * fcw[i][t]  (fcw read ONCE per block)
  const float* fcwp = fcw + (size_t)v*H*H + t;
  const float fcbv = fcb[v*H+t];
  float g[TN3];
  #pragma unroll
  for (int r=0;r<TN3;r++) g[r] = fcbv;
  for (int i=0;i<H;i++){
    float fw = fcwp[(size_t)i*H];
    float4 a0 = *(const float4*)&As2T[i][0];
    float4 a1v = *(const float4*)&As2T[i][4];
    g[0] = fmaf(a0.x, fw, g[0]);  g[1] = fmaf(a0.y, fw, g[1]);
    g[2] = fmaf(a0.z, fw, g[2]);  g[3] = fmaf(a0.w, fw, g[3]);
    g[4] = fmaf(a1v.x, fw, g[4]); g[5] = fmaf(a1v.y, fw, g[5]);
    g[6] = fmaf(a1v.z, fw, g[6]); g[7] = fmaf(a1v.w, fw, g[7]);
  }
  const float cwv = confw[v*H+t];
  const float cbv = confb[v];
  #pragma unroll
  for (int r=0;r<TN3;r++){
    g[r] = fmaxf(g[r], 0.f);
    float psm = g[r]*cwv;
    #pragma unroll
    for (int o=32;o>0;o>>=1) psm += __shfl_down(psm,o);
    if (lane==0) rbuf2[r][W] = psm;
  }
  __syncthreads();
  #pragma unroll
  for (int r=0;r<TN3;r++){
    const float conf = rbuf2[r][0] + rbuf2[r][1] + cbv;
    feat2[((size_t)v*N + n0 + r)*H + t] = g[r]*conf;
  }
}

// ---------------- K4: final classifier [N, V*H] @ [V*H, C] ----------------
__global__ __launch_bounds__(64) void k4_cls(
    const float* __restrict__ feat2,
    const float* __restrict__ mm_w, const float* __restrict__ mm_b,
    float* __restrict__ out)
{
  const int n = blockIdx.x, t = threadIdx.x;
  float a[C] = {0,0,0,0,0};
  for (int j=t; j<V*H; j+=64){
    int vv = j >> 7, hh = j & (H-1);
    float f = feat2[((size_t)vv*N + n)*H + hh];
    #pragma unroll
    for (int c=0;c<C;c++) a[c] = fmaf(f, mm_w[j*C+c], a[c]);
  }
  #pragma unroll
  for (int c=0;c<C;c++){
    #pragma unroll
    for (int o=32;o>0;o>>=1) a[c] += __shfl_down(a[c],o);
  }
  if (t==0){
    #pragma unroll
    for (int c=0;c<C;c++) out[(size_t)n*C+c] = a[c] + mm_b[c];
  }
}

extern "C" void kernel_launch(void* const* d_in, const int* in_sizes, int n_in,
                              void* d_out, int out_size, void* d_ws, size_t ws_size,
                              hipStream_t stream)
{
  (void)in_sizes; (void)n_in; (void)out_size; (void)ws_size;
  const float* data  = (const float*)d_in[0];
  const int*   adj   = (const int*)d_in[1];
  const float* gac_w = (const float*)d_in[2];
  const float* gac_b = (const float*)d_in[3];
  const float* a1    = (const float*)d_in[4];
  const float* a2    = (const float*)d_in[5];
  const float* mlp_w = (const float*)d_in[6];
  const float* mlp_b = (const float*)d_in[7];
  const float* q_w   = (const float*)d_in[8];
  const float* q_b   = (const float*)d_in[9];
  const float* k_w   = (const float*)d_in[10];
  const float* k_b   = (const float*)d_in[11];
  const float* v_w   = (const float*)d_in[12];
  const float* v_b   = (const float*)d_in[13];
  const float* fc_w  = (const float*)d_in[14];
  const float* fc_b  = (const float*)d_in[15];
  const float* cw    = (const float*)d_in[16];
  const float* cb    = (const float*)d_in[17];
  const float* mm_w  = (const float*)d_in[18];
  const float* mm_b  = (const float*)d_in[19];

  float* ws = (float*)d_ws;
  const size_t VNH = (size_t)V*N*H;
  float* mlp   = ws;
  float* feat  = ws + VNH;
  float* feat2 = ws + 2*VNH;
  float* e1    = ws + 3*VNH;
  float* e2    = e1 + (size_t)V*N;
  unsigned short* hT = (unsigned short*)(e2 + (size_t)V*N);  // [V][H][N] bf16

  k1_gemm<<<dim3(N/TN1, V), 256, 0, stream>>>(data, gac_w, mlp_w, a1, a2,
                                              hT, mlp, e1, e2);
  k2_attn<<<dim3(N/16, V),  512, 0, stream>>>(hT, adj, e1, e2, mlp, gac_b, mlp_b, feat);
  k3_sgfe<<<dim3(N/TN3, V), 128, 0, stream>>>(feat, q_w, q_b, k_w, k_b, v_w, v_b,
                                              fc_w, fc_b, cw, cb, feat2);
  k4_cls<<<dim3(N),          64, 0, stream>>>(feat2, mm_w, mm_b, (float*)d_out);
}